// Round 6
// baseline (181.101 us; speedup 1.0000x reference)
//
#include <hip/hip_runtime.h>

#define F_IN 128
#define HH1 128
#define HH2 64
#define FOUT 50

typedef __attribute__((ext_vector_type(8))) short short8;
typedef __attribute__((ext_vector_type(4))) short s16x4;
typedef __attribute__((ext_vector_type(4))) float f32x4;

__device__ inline short f2bf(float f) {  // RNE fp32->bf16
    union { float f; unsigned u; } v; v.f = f;
    unsigned r = v.u + 0x7fffu + ((v.u >> 16) & 1u);
    return (short)(r >> 16);
}
__device__ inline float bf2f(short s) {
    union { float f; unsigned u; } v; v.u = ((unsigned)(unsigned short)s) << 16;
    return v.f;
}

// ---- fused: detect edge dtype (block 0) + zero count8 (all blocks) ----------
__global__ void init_kernel(const unsigned int* __restrict__ raw, int* __restrict__ flag,
                            int4* __restrict__ cnt, int n4) {
    if (blockIdx.x == 0) {
        __shared__ int nonzero;
        if (threadIdx.x == 0) nonzero = 0;
        __syncthreads();
        if (raw[2 * threadIdx.x + 1] != 0u) atomicOr(&nonzero, 1);
        __syncthreads();
        if (threadIdx.x == 0) *flag = (nonzero ? 0 : 1);  // 1 => int64
    }
    int i = blockIdx.x * 256 + threadIdx.x;
    int stride = gridDim.x * 256;
    for (; i < n4; i += stride) cnt[i] = make_int4(0, 0, 0, 0);
}

// ---- convert edges to int2 + sharded in-degree count ------------------------
// count8[d*8 + (e&7)]: adjacent lanes hit distinct shards -> ~no same-addr collisions
__global__ void prep_count(const int* __restrict__ raw, const int* __restrict__ flag,
                           int2* __restrict__ edges, int* __restrict__ count8, int E) {
    int e = blockIdx.x * 256 + threadIdx.x;
    if (e >= E) return;
    int is64 = *flag;
    int s, d;
    if (is64) {
        s = raw[2 * e];
        d = raw[2 * (long)E + 2 * e];
    } else {
        s = raw[e];
        d = raw[E + e];
    }
    edges[e] = make_int2(s, d);
    atomicAdd(&count8[d * 8 + (e & 7)], 1);
}

// ---- 3-level exclusive scan over count8[0..n8) ------------------------------
__global__ void scan_l1(int* __restrict__ arr, int* __restrict__ bsums, int n8) {
    __shared__ int sh[256];
    int tid = threadIdx.x;
    int gid = blockIdx.x * 256 + tid;
    int v = (gid < n8) ? arr[gid] : 0;
    sh[tid] = v;
    __syncthreads();
    for (int off = 1; off < 256; off <<= 1) {
        int t = (tid >= off) ? sh[tid - off] : 0;
        __syncthreads();
        sh[tid] += t;
        __syncthreads();
    }
    if (gid < n8) arr[gid] = sh[tid] - v;  // exclusive within block
    if (tid == 255) bsums[blockIdx.x] = sh[255];
}
__global__ void scan_l2(int* __restrict__ bsums, int nb) {
    __shared__ int sh[256];
    __shared__ int carry;
    int tid = threadIdx.x;
    if (tid == 0) carry = 0;
    __syncthreads();
    for (int base = 0; base < nb; base += 256) {
        int i = base + tid;
        int v = (i < nb) ? bsums[i] : 0;
        sh[tid] = v;
        __syncthreads();
        for (int off = 1; off < 256; off <<= 1) {
            int t = (tid >= off) ? sh[tid - off] : 0;
            __syncthreads();
            sh[tid] += t;
            __syncthreads();
        }
        if (i < nb) bsums[i] = sh[tid] - v + carry;  // exclusive + carry
        __syncthreads();
        if (tid == 0) carry += sh[255];
        __syncthreads();
    }
}
__global__ void scan_l3(int* __restrict__ arr, const int* __restrict__ bsums, int n8) {
    int gid = blockIdx.x * 256 + threadIdx.x;
    if (gid < n8) arr[gid] += bsums[gid >> 8];
}

// ---- extract rowptr + dinv from scanned base --------------------------------
__global__ void finalize_csr(const int* __restrict__ base, int* __restrict__ rowptr,
                             float* __restrict__ dinv, int n, int E) {
    int d = blockIdx.x * 256 + threadIdx.x;
    if (d >= n) return;
    int r0 = base[d * 8];
    int r1 = (d == n - 1) ? E : base[(d + 1) * 8];
    rowptr[d] = r0;
    if (d == 0) rowptr[n] = E;
    dinv[d] = rsqrtf((float)(r1 - r0) + 1.0f);  // +1 self-loop
}

// ---- sharded scatter: atomics on cursor[d*8+(e&7)], contention /8 -----------
__global__ void scatter8(const int2* __restrict__ edges, const float* __restrict__ dinv,
                         int* __restrict__ cursor, uint2* __restrict__ csr, int E) {
    int t = blockIdx.x * 256 + threadIdx.x;
    int stride = gridDim.x * 256;  // multiple of 8 -> shard stable per thread
    for (int e = t; e < E; e += stride) {
        int2 sd = edges[e];
        float c = dinv[sd.x] * dinv[sd.y];
        int pos = atomicAdd(&cursor[sd.y * 8 + (e & 7)], 1);
        csr[pos] = make_uint2((unsigned)sd.x, __float_as_uint(c));
    }
}

// ---- all weights -> bf16 transposed, one kernel -----------------------------
__global__ void wtrans_all(const float* __restrict__ W1, const float* __restrict__ W2,
                           const float* __restrict__ Wh, short* __restrict__ W1t,
                           short* __restrict__ W2t, short* __restrict__ Wht) {
    const int T1 = HH1 * F_IN, T2 = HH2 * HH1, T3 = 64 * HH2;
    int idx = blockIdx.x * 256 + threadIdx.x;
    if (idx < T1) {
        int c = idx / F_IN, k = idx - c * F_IN;
        W1t[idx] = f2bf(W1[(long)k * HH1 + c]);
    } else if (idx < T1 + T2) {
        int i = idx - T1;
        int c = i / HH1, k = i - c * HH1;
        W2t[i] = f2bf(W2[(long)k * HH2 + c]);
    } else if (idx < T1 + T2 + T3) {
        int i = idx - T1 - T2;
        int c = i / HH2, k = i - c * HH2;
        Wht[i] = f2bf((c < FOUT) ? Wh[(long)k * FOUT + c] : 0.f);
    }
}

// ---- MFMA GEMM: Y[M,NC] = X[M,K] @ Wt^T, per-wave 16-row tile ---------------
template <int K, int NC, bool IN_BF16, bool OUT_F32, bool BIAS>
__global__ __launch_bounds__(256) void mfma_gemm(const void* __restrict__ Xv,
                                                 const short* __restrict__ Wt,
                                                 const float* __restrict__ bias,
                                                 void* __restrict__ Yv, int M, int NCOUT) {
    const int tid = threadIdx.x;
    const int wave = tid >> 6;
    const int lane = tid & 63;
    const int l15 = lane & 15;
    const int kg = lane >> 4;
    const int rowbase = blockIdx.x * 64 + wave * 16;
    const int arow = rowbase + l15;
    constexpr int KS = K / 32;

    short8 af[KS];
    if (arow < M) {
        if (IN_BF16) {
            const short* xr = (const short*)Xv + (long)arow * K + kg * 8;
#pragma unroll
            for (int ks = 0; ks < KS; ++ks) af[ks] = *(const short8*)(xr + ks * 32);
        } else {
            const float* xr = (const float*)Xv + (long)arow * K + kg * 8;
#pragma unroll
            for (int ks = 0; ks < KS; ++ks) {
                float4 f0 = *(const float4*)(xr + ks * 32);
                float4 f1 = *(const float4*)(xr + ks * 32 + 4);
                short8 a;
                a[0] = f2bf(f0.x); a[1] = f2bf(f0.y); a[2] = f2bf(f0.z); a[3] = f2bf(f0.w);
                a[4] = f2bf(f1.x); a[5] = f2bf(f1.y); a[6] = f2bf(f1.z); a[7] = f2bf(f1.w);
                af[ks] = a;
            }
        }
    } else {
#pragma unroll
        for (int ks = 0; ks < KS; ++ks) af[ks] = (short8)0;
    }

    const int crowb = rowbase + kg * 4;
#pragma unroll
    for (int ct = 0; ct < NC / 16; ++ct) {
        const int col = ct * 16 + l15;
        const short* wr = Wt + (long)col * K + kg * 8;
        f32x4 acc = {0.f, 0.f, 0.f, 0.f};
#pragma unroll
        for (int ks = 0; ks < KS; ++ks) {
            short8 bf = *(const short8*)(wr + ks * 32);
            acc = __builtin_amdgcn_mfma_f32_16x16x32_bf16(af[ks], bf, acc, 0, 0, 0);
        }
        if (OUT_F32) {
            float* Y = (float*)Yv;
            float bv = BIAS ? bias[col] : 0.f;
#pragma unroll
            for (int j = 0; j < 4; ++j) {
                int r = crowb + j;
                if (r < M && col < NCOUT) Y[(long)r * NCOUT + col] = acc[j] + bv;
            }
        } else {
            short* Y = (short*)Yv;
#pragma unroll
            for (int j = 0; j < 4; ++j) {
                int r = crowb + j;
                if (r < M) Y[(long)r * NC + col] = f2bf(acc[j]);
            }
        }
    }
}

// ---- CSR aggregation, bf16 features, packed edges, 4-wide ILP ---------------
// agg[i] = relu(bias + dinv[i]^2*h[i] + sum_e coef*h[src]) -> bf16
template <int LPN, int NPB>
__global__ __launch_bounds__(256) void agg_csr_bf16(const short* __restrict__ h,
                                                    const int* __restrict__ rowptr,
                                                    const uint2* __restrict__ csr,
                                                    const float* __restrict__ dinv,
                                                    const float* __restrict__ bias,
                                                    short* __restrict__ agg, int n) {
    const int tid = threadIdx.x;
    const int node = blockIdx.x * NPB + tid / LPN;
    const int lane = tid % LPN;
    if (node >= n) return;
    const s16x4* __restrict__ h4 = (const s16x4*)h;

    float4 acc = ((const float4*)bias)[lane];
    float di = dinv[node];
    float cs = di * di;
    s16x4 hv = h4[(long)node * LPN + lane];
    acc.x = fmaf(cs, bf2f(hv[0]), acc.x);
    acc.y = fmaf(cs, bf2f(hv[1]), acc.y);
    acc.z = fmaf(cs, bf2f(hv[2]), acc.z);
    acc.w = fmaf(cs, bf2f(hv[3]), acc.w);

    int e = rowptr[node];
    const int end = rowptr[node + 1];
    for (; e + 3 < end; e += 4) {
        uint2 p0 = csr[e];
        uint2 p1 = csr[e + 1];
        uint2 p2 = csr[e + 2];
        uint2 p3 = csr[e + 3];
        s16x4 v0 = h4[(long)p0.x * LPN + lane];
        s16x4 v1 = h4[(long)p1.x * LPN + lane];
        s16x4 v2 = h4[(long)p2.x * LPN + lane];
        s16x4 v3 = h4[(long)p3.x * LPN + lane];
        float c0 = __uint_as_float(p0.y);
        float c1 = __uint_as_float(p1.y);
        float c2 = __uint_as_float(p2.y);
        float c3 = __uint_as_float(p3.y);
        acc.x = fmaf(c0, bf2f(v0[0]), acc.x);
        acc.y = fmaf(c0, bf2f(v0[1]), acc.y);
        acc.z = fmaf(c0, bf2f(v0[2]), acc.z);
        acc.w = fmaf(c0, bf2f(v0[3]), acc.w);
        acc.x = fmaf(c1, bf2f(v1[0]), acc.x);
        acc.y = fmaf(c1, bf2f(v1[1]), acc.y);
        acc.z = fmaf(c1, bf2f(v1[2]), acc.z);
        acc.w = fmaf(c1, bf2f(v1[3]), acc.w);
        acc.x = fmaf(c2, bf2f(v2[0]), acc.x);
        acc.y = fmaf(c2, bf2f(v2[1]), acc.y);
        acc.z = fmaf(c2, bf2f(v2[2]), acc.z);
        acc.w = fmaf(c2, bf2f(v2[3]), acc.w);
        acc.x = fmaf(c3, bf2f(v3[0]), acc.x);
        acc.y = fmaf(c3, bf2f(v3[1]), acc.y);
        acc.z = fmaf(c3, bf2f(v3[2]), acc.z);
        acc.w = fmaf(c3, bf2f(v3[3]), acc.w);
    }
    for (; e < end; ++e) {
        uint2 p0 = csr[e];
        float c0 = __uint_as_float(p0.y);
        s16x4 v0 = h4[(long)p0.x * LPN + lane];
        acc.x = fmaf(c0, bf2f(v0[0]), acc.x);
        acc.y = fmaf(c0, bf2f(v0[1]), acc.y);
        acc.z = fmaf(c0, bf2f(v0[2]), acc.z);
        acc.w = fmaf(c0, bf2f(v0[3]), acc.w);
    }
    s16x4 o;
    o[0] = f2bf(fmaxf(acc.x, 0.f));
    o[1] = f2bf(fmaxf(acc.y, 0.f));
    o[2] = f2bf(fmaxf(acc.z, 0.f));
    o[3] = f2bf(fmaxf(acc.w, 0.f));
    ((s16x4*)agg)[(long)node * LPN + lane] = o;
}

// ---- launch -----------------------------------------------------------------
static inline size_t al256(size_t x) { return (x + 255) & ~(size_t)255; }

extern "C" void kernel_launch(void* const* d_in, const int* in_sizes, int n_in,
                              void* d_out, int out_size, void* d_ws, size_t ws_size,
                              hipStream_t stream) {
    const float* x    = (const float*)d_in[0];
    const int*   eraw = (const int*)d_in[1];
    const float* W1   = (const float*)d_in[2];
    const float* b1   = (const float*)d_in[3];
    const float* W2   = (const float*)d_in[4];
    const float* b2   = (const float*)d_in[5];
    const float* Wh   = (const float*)d_in[6];
    const float* bh   = (const float*)d_in[7];
    float* out = (float*)d_out;
    const int n = in_sizes[0] / F_IN;
    const int E = in_sizes[1] / 2;
    const int n8 = 8 * n;
    const int nb1 = (n8 + 255) / 256;   // scan L1 blocks (1563 for n=50k)

    // ---- workspace layout ----
    char* p = (char*)d_ws;
    int*   flag     = (int*)p;   p += 256;
    float* dinv     = (float*)p; p += al256((size_t)n * 4);
    int*   rowptr   = (int*)p;   p += al256((size_t)(n + 1) * 4);
    int*   bsums    = (int*)p;   p += al256((size_t)nb1 * 4);
    int*   count8   = (int*)p;   p += al256((size_t)n8 * 4);       // count -> base -> cursor
    uint2* csr      = (uint2*)p; p += al256((size_t)E * 8);
    short* W1t      = (short*)p; p += al256((size_t)HH1 * F_IN * 2);
    short* W2t      = (short*)p; p += al256((size_t)HH2 * HH1 * 2);
    short* Whtp     = (short*)p; p += al256((size_t)64 * HH2 * 2);
    short* bigA     = (short*)p; p += al256((size_t)n * HH1 * 2);   // 12.8 MB
    short* bigB     = (short*)p;                                    // 12.8 MB
    // int2 edge list overlays bigA (dead before GEMM1 writes h1)
    int2* edges = (int2*)bigA;
    short* h1   = bigA;
    short* agg1 = bigB;
    short* h2   = bigA;                          // 6.4 MB
    short* agg2 = bigA + (size_t)n * HH2;        // disjoint from h2

    dim3 blk(256);
    // graph prep: detect + zero counters, sharded count, 3-level scan, finalize, scatter
    init_kernel<<<256, blk, 0, stream>>>((const unsigned int*)eraw, flag, (int4*)count8, n8 / 4);
    prep_count<<<(E + 255) / 256, blk, 0, stream>>>(eraw, flag, edges, count8, E);
    scan_l1<<<nb1, blk, 0, stream>>>(count8, bsums, n8);
    scan_l2<<<1, blk, 0, stream>>>(bsums, nb1);
    scan_l3<<<nb1, blk, 0, stream>>>(count8, bsums, n8);
    finalize_csr<<<(n + 255) / 256, blk, 0, stream>>>(count8, rowptr, dinv, n, E);
    scatter8<<<(E + 511) / 512, blk, 0, stream>>>(edges, dinv, count8, csr, E);
    wtrans_all<<<(HH1 * F_IN + HH2 * HH1 + 64 * HH2 + 255) / 256, blk, 0, stream>>>(
        W1, W2, Wh, W1t, W2t, Whtp);

    const int gblocks = (n + 63) / 64;
    // layer 1: h1 = x @ W1 (bf16 out)
    mfma_gemm<F_IN, HH1, false, false, false><<<gblocks, blk, 0, stream>>>(x, W1t, nullptr, h1, n, HH1);
    agg_csr_bf16<32, 8><<<(n + 7) / 8, blk, 0, stream>>>(h1, rowptr, csr, dinv, b1, agg1, n);
    // layer 2: h2 = agg1 @ W2
    mfma_gemm<HH1, HH2, true, false, false><<<gblocks, blk, 0, stream>>>(agg1, W2t, nullptr, h2, n, HH2);
    agg_csr_bf16<16, 16><<<(n + 15) / 16, blk, 0, stream>>>(h2, rowptr, csr, dinv, b2, agg2, n);
    // head: out = agg2 @ Wh + bh (fp32 out, masked to 50 cols)
    mfma_gemm<HH2, 64, true, true, true><<<gblocks, blk, 0, stream>>>(agg2, Whtp, bh, out, n, FOUT);
}

// Round 7
// 148.764 us; speedup vs baseline: 1.2174x; 1.2174x over previous
//
#include <hip/hip_runtime.h>

#define F_IN 128
#define HH1 128
#define HH2 64
#define FOUT 50
#define EB 256          // edge-pass blocks (A1/A3)
#define NBUCK_MAX 256   // max coarse buckets (n <= 64k)

typedef __attribute__((ext_vector_type(8))) short short8;
typedef __attribute__((ext_vector_type(4))) short s16x4;
typedef __attribute__((ext_vector_type(4))) float f32x4;

__device__ inline short f2bf(float f) {  // RNE fp32->bf16
    union { float f; unsigned u; } v; v.f = f;
    unsigned r = v.u + 0x7fffu + ((v.u >> 16) & 1u);
    return (short)(r >> 16);
}
__device__ inline float bf2f(short s) {
    union { float f; unsigned u; } v; v.u = ((unsigned)(unsigned short)s) << 16;
    return v.f;
}

// Per-block int64-vs-int32 self-detection: int64 node ids < 2^31 have all-zero
// high (odd) words in the first 512 int32 words. Returns 1 if int64.
__device__ inline int detect64(const unsigned* raw) {
    __shared__ int s_is64;
    if (threadIdx.x == 0) s_is64 = 1;
    __syncthreads();
    if (raw[2 * threadIdx.x + 1] != 0u) atomicAnd(&s_is64, 0);
    __syncthreads();
    return s_is64;
}

// ---- A1: coarse histogram (dst>>8) per block + fused weight transpose -------
__global__ __launch_bounds__(256) void bucket_count(
    const int* __restrict__ raw, int E, int nbuck, int* __restrict__ parthist,
    const float* __restrict__ W1, const float* __restrict__ W2,
    const float* __restrict__ Wh, short* __restrict__ W1t,
    short* __restrict__ W2t, short* __restrict__ Wht) {
    __shared__ int hist[NBUCK_MAX];
    const int tid = threadIdx.x;
    int is64 = detect64((const unsigned*)raw);
    for (int k = tid; k < nbuck; k += 256) hist[k] = 0;
    __syncthreads();
    const int CH = (E + EB - 1) / EB;
    const int e0 = blockIdx.x * CH, e1 = min(E, e0 + CH);
    for (int e = e0 + tid; e < e1; e += 256) {
        int d = is64 ? raw[2 * (long)E + 2 * e] : raw[E + e];
        atomicAdd(&hist[d >> 8], 1);
    }
    __syncthreads();
    for (int k = tid; k < nbuck; k += 256) parthist[blockIdx.x * nbuck + k] = hist[k];
    // fused weight transpose (independent work)
    const int T1 = HH1 * F_IN, T2 = HH2 * HH1, T3 = 64 * HH2;
    int idx = blockIdx.x * 256 + tid;
    if (idx < T1) {
        int c = idx / F_IN, k = idx - c * F_IN;
        W1t[idx] = f2bf(W1[(long)k * HH1 + c]);
    } else if (idx < T1 + T2) {
        int i = idx - T1;
        int c = i / HH1, k = i - c * HH1;
        W2t[i] = f2bf(W2[(long)k * HH2 + c]);
    } else if (idx < T1 + T2 + T3) {
        int i = idx - T1 - T2;
        int c = i / HH2, k = i - c * HH2;
        Wht[i] = f2bf((c < FOUT) ? Wh[(long)k * FOUT + c] : 0.f);
    }
}

// ---- A2: column-sum + scan -> bucket bases; parthist -> per-block offsets ---
__global__ __launch_bounds__(256) void bucket_scan(
    int* __restrict__ parthist, int* __restrict__ bbase, int nbuck, int E) {
    __shared__ int sh[256];
    const int k = threadIdx.x;
    int sum = 0;
    if (k < nbuck)
        for (int b = 0; b < EB; ++b) sum += parthist[b * nbuck + k];
    int v = (k < nbuck) ? sum : 0;
    sh[k] = v;
    __syncthreads();
    for (int off = 1; off < 256; off <<= 1) {
        int t = (k >= off) ? sh[k - off] : 0;
        __syncthreads();
        sh[k] += t;
        __syncthreads();
    }
    int base = sh[k] - v;  // exclusive
    if (k < nbuck) bbase[k] = base;
    if (k == 0) bbase[nbuck] = E;
    if (k < nbuck) {
        int run = base;
        for (int b = 0; b < EB; ++b) {
            int t = parthist[b * nbuck + k];
            parthist[b * nbuck + k] = run;
            run += t;
        }
    }
}

// ---- A3: scatter (src,dst) into coarse buckets via LDS cursors --------------
__global__ __launch_bounds__(256) void bucket_scatter(
    const int* __restrict__ raw, int E, int nbuck,
    const int* __restrict__ parthist, int2* __restrict__ tmp) {
    __shared__ int cur[NBUCK_MAX];
    const int tid = threadIdx.x;
    int is64 = detect64((const unsigned*)raw);
    for (int k = tid; k < nbuck; k += 256) cur[k] = parthist[blockIdx.x * nbuck + k];
    __syncthreads();
    const int CH = (E + EB - 1) / EB;
    const int e0 = blockIdx.x * CH, e1 = min(E, e0 + CH);
    for (int e = e0 + tid; e < e1; e += 256) {
        int s, d;
        if (is64) {
            s = raw[2 * e];
            d = raw[2 * (long)E + 2 * e];
        } else {
            s = raw[e];
            d = raw[E + e];
        }
        int pos = atomicAdd(&cur[d >> 8], 1);
        tmp[pos] = make_int2(s, d);
    }
}

// ---- B: per-bucket fine sort -> rowptr, dinv, csr_src -----------------------
__global__ __launch_bounds__(256) void bucket_finalize(
    const int2* __restrict__ tmp, const int* __restrict__ bbase,
    int* __restrict__ rowptr, float* __restrict__ dinv,
    int* __restrict__ csr_src, int n, int nbuck) {
    __shared__ int deg[256];
    __shared__ int cur[256];
    __shared__ int sh[256];
    const int k = blockIdx.x;
    const int tid = threadIdx.x;
    const int b0 = bbase[k], b1 = bbase[k + 1];
    deg[tid] = 0;
    __syncthreads();
    for (int e = b0 + tid; e < b1; e += 256) atomicAdd(&deg[tmp[e].y & 255], 1);
    __syncthreads();
    int v = deg[tid];
    sh[tid] = v;
    __syncthreads();
    for (int off = 1; off < 256; off <<= 1) {
        int t = (tid >= off) ? sh[tid - off] : 0;
        __syncthreads();
        sh[tid] += t;
        __syncthreads();
    }
    int excl = sh[tid] - v;
    cur[tid] = excl;
    int node = (k << 8) + tid;
    if (node < n) {
        rowptr[node] = b0 + excl;
        dinv[node] = rsqrtf((float)v + 1.0f);  // +1 self-loop
    }
    if (k == 0 && tid == 0) rowptr[n] = bbase[nbuck];
    __syncthreads();
    for (int e = b0 + tid; e < b1; e += 256) {
        int2 sd = tmp[e];
        int p = atomicAdd(&cur[sd.y & 255], 1);
        csr_src[b0 + p] = sd.x;
    }
}

// ---- MFMA GEMM: Y[M,NC] = X[M,K] @ Wt^T, per-wave 16-row tile ---------------
template <int K, int NC, bool IN_BF16, bool OUT_F32, bool BIAS>
__global__ __launch_bounds__(256) void mfma_gemm(const void* __restrict__ Xv,
                                                 const short* __restrict__ Wt,
                                                 const float* __restrict__ bias,
                                                 void* __restrict__ Yv, int M, int NCOUT) {
    const int tid = threadIdx.x;
    const int wave = tid >> 6;
    const int lane = tid & 63;
    const int l15 = lane & 15;
    const int kg = lane >> 4;
    const int rowbase = blockIdx.x * 64 + wave * 16;
    const int arow = rowbase + l15;
    constexpr int KS = K / 32;

    short8 af[KS];
    if (arow < M) {
        if (IN_BF16) {
            const short* xr = (const short*)Xv + (long)arow * K + kg * 8;
#pragma unroll
            for (int ks = 0; ks < KS; ++ks) af[ks] = *(const short8*)(xr + ks * 32);
        } else {
            const float* xr = (const float*)Xv + (long)arow * K + kg * 8;
#pragma unroll
            for (int ks = 0; ks < KS; ++ks) {
                float4 f0 = *(const float4*)(xr + ks * 32);
                float4 f1 = *(const float4*)(xr + ks * 32 + 4);
                short8 a;
                a[0] = f2bf(f0.x); a[1] = f2bf(f0.y); a[2] = f2bf(f0.z); a[3] = f2bf(f0.w);
                a[4] = f2bf(f1.x); a[5] = f2bf(f1.y); a[6] = f2bf(f1.z); a[7] = f2bf(f1.w);
                af[ks] = a;
            }
        }
    } else {
#pragma unroll
        for (int ks = 0; ks < KS; ++ks) af[ks] = (short8)0;
    }

    const int crowb = rowbase + kg * 4;
#pragma unroll
    for (int ct = 0; ct < NC / 16; ++ct) {
        const int col = ct * 16 + l15;
        const short* wr = Wt + (long)col * K + kg * 8;
        f32x4 acc = {0.f, 0.f, 0.f, 0.f};
#pragma unroll
        for (int ks = 0; ks < KS; ++ks) {
            short8 bf = *(const short8*)(wr + ks * 32);
            acc = __builtin_amdgcn_mfma_f32_16x16x32_bf16(af[ks], bf, acc, 0, 0, 0);
        }
        if (OUT_F32) {
            float* Y = (float*)Yv;
            float bv = BIAS ? bias[col] : 0.f;
#pragma unroll
            for (int j = 0; j < 4; ++j) {
                int r = crowb + j;
                if (r < M && col < NCOUT) Y[(long)r * NCOUT + col] = acc[j] + bv;
            }
        } else {
            short* Y = (short*)Yv;
#pragma unroll
            for (int j = 0; j < 4; ++j) {
                int r = crowb + j;
                if (r < M) Y[(long)r * NC + col] = f2bf(acc[j]);
            }
        }
    }
}

// ---- CSR aggregation, bf16 features, src-only CSR, on-the-fly coef ----------
// agg[i] = relu(bias + dinv[i]^2*h[i] + sum_e dinv[src]*dinv[i]*h[src]) -> bf16
template <int LPN, int NPB>
__global__ __launch_bounds__(256) void agg_csr_bf16(const short* __restrict__ h,
                                                    const int* __restrict__ rowptr,
                                                    const int* __restrict__ csr_src,
                                                    const float* __restrict__ dinv,
                                                    const float* __restrict__ bias,
                                                    short* __restrict__ agg, int n) {
    const int tid = threadIdx.x;
    const int node = blockIdx.x * NPB + tid / LPN;
    const int lane = tid % LPN;
    if (node >= n) return;
    const s16x4* __restrict__ h4 = (const s16x4*)h;

    const float di = dinv[node];
    float4 acc = ((const float4*)bias)[lane];
    float cs = di * di;
    s16x4 hv = h4[(long)node * LPN + lane];
    acc.x = fmaf(cs, bf2f(hv[0]), acc.x);
    acc.y = fmaf(cs, bf2f(hv[1]), acc.y);
    acc.z = fmaf(cs, bf2f(hv[2]), acc.z);
    acc.w = fmaf(cs, bf2f(hv[3]), acc.w);

    int e = rowptr[node];
    const int end = rowptr[node + 1];
    for (; e + 3 < end; e += 4) {
        int s0 = csr_src[e];
        int s1 = csr_src[e + 1];
        int s2 = csr_src[e + 2];
        int s3 = csr_src[e + 3];
        s16x4 v0 = h4[(long)s0 * LPN + lane];
        s16x4 v1 = h4[(long)s1 * LPN + lane];
        s16x4 v2 = h4[(long)s2 * LPN + lane];
        s16x4 v3 = h4[(long)s3 * LPN + lane];
        float c0 = dinv[s0] * di;
        float c1 = dinv[s1] * di;
        float c2 = dinv[s2] * di;
        float c3 = dinv[s3] * di;
        acc.x = fmaf(c0, bf2f(v0[0]), acc.x);
        acc.y = fmaf(c0, bf2f(v0[1]), acc.y);
        acc.z = fmaf(c0, bf2f(v0[2]), acc.z);
        acc.w = fmaf(c0, bf2f(v0[3]), acc.w);
        acc.x = fmaf(c1, bf2f(v1[0]), acc.x);
        acc.y = fmaf(c1, bf2f(v1[1]), acc.y);
        acc.z = fmaf(c1, bf2f(v1[2]), acc.z);
        acc.w = fmaf(c1, bf2f(v1[3]), acc.w);
        acc.x = fmaf(c2, bf2f(v2[0]), acc.x);
        acc.y = fmaf(c2, bf2f(v2[1]), acc.y);
        acc.z = fmaf(c2, bf2f(v2[2]), acc.z);
        acc.w = fmaf(c2, bf2f(v2[3]), acc.w);
        acc.x = fmaf(c3, bf2f(v3[0]), acc.x);
        acc.y = fmaf(c3, bf2f(v3[1]), acc.y);
        acc.z = fmaf(c3, bf2f(v3[2]), acc.z);
        acc.w = fmaf(c3, bf2f(v3[3]), acc.w);
    }
    for (; e < end; ++e) {
        int s0 = csr_src[e];
        float c0 = dinv[s0] * di;
        s16x4 v0 = h4[(long)s0 * LPN + lane];
        acc.x = fmaf(c0, bf2f(v0[0]), acc.x);
        acc.y = fmaf(c0, bf2f(v0[1]), acc.y);
        acc.z = fmaf(c0, bf2f(v0[2]), acc.z);
        acc.w = fmaf(c0, bf2f(v0[3]), acc.w);
    }
    s16x4 o;
    o[0] = f2bf(fmaxf(acc.x, 0.f));
    o[1] = f2bf(fmaxf(acc.y, 0.f));
    o[2] = f2bf(fmaxf(acc.z, 0.f));
    o[3] = f2bf(fmaxf(acc.w, 0.f));
    ((s16x4*)agg)[(long)node * LPN + lane] = o;
}

// ---- launch -----------------------------------------------------------------
static inline size_t al256(size_t x) { return (x + 255) & ~(size_t)255; }

extern "C" void kernel_launch(void* const* d_in, const int* in_sizes, int n_in,
                              void* d_out, int out_size, void* d_ws, size_t ws_size,
                              hipStream_t stream) {
    const float* x    = (const float*)d_in[0];
    const int*   eraw = (const int*)d_in[1];
    const float* W1   = (const float*)d_in[2];
    const float* b1   = (const float*)d_in[3];
    const float* W2   = (const float*)d_in[4];
    const float* b2   = (const float*)d_in[5];
    const float* Wh   = (const float*)d_in[6];
    const float* bh   = (const float*)d_in[7];
    float* out = (float*)d_out;
    const int n = in_sizes[0] / F_IN;
    const int E = in_sizes[1] / 2;
    const int nbuck = (n + 255) >> 8;  // 196 for n=50k (<= NBUCK_MAX)

    // ---- workspace layout ----
    char* p = (char*)d_ws;
    float* dinv     = (float*)p; p += al256((size_t)n * 4);
    int*   rowptr   = (int*)p;   p += al256((size_t)(n + 1) * 4);
    int*   parthist = (int*)p;   p += al256((size_t)EB * nbuck * 4);
    int*   bbase    = (int*)p;   p += al256((size_t)(nbuck + 1) * 4);
    int*   csr_src  = (int*)p;   p += al256((size_t)E * 4);
    short* W1t      = (short*)p; p += al256((size_t)HH1 * F_IN * 2);
    short* W2t      = (short*)p; p += al256((size_t)HH2 * HH1 * 2);
    short* Whtp     = (short*)p; p += al256((size_t)64 * HH2 * 2);
    short* bigA     = (short*)p; p += al256((size_t)n * HH1 * 2);   // 12.8 MB
    short* bigB     = (short*)p;                                    // 12.8 MB
    // (src,dst) bucket buffer overlays bigA (dead before GEMM1 writes h1)
    int2* tmp   = (int2*)bigA;
    short* h1   = bigA;
    short* agg1 = bigB;
    short* h2   = bigA;                          // 6.4 MB
    short* agg2 = bigA + (size_t)n * HH2;        // disjoint from h2

    dim3 blk(256);
    // CSR build: two-level bucket sort, all fine atomics in LDS
    bucket_count<<<EB, blk, 0, stream>>>(eraw, E, nbuck, parthist, W1, W2, Wh, W1t, W2t, Whtp);
    bucket_scan<<<1, blk, 0, stream>>>(parthist, bbase, nbuck, E);
    bucket_scatter<<<EB, blk, 0, stream>>>(eraw, E, nbuck, parthist, tmp);
    bucket_finalize<<<nbuck, blk, 0, stream>>>(tmp, bbase, rowptr, dinv, csr_src, n, nbuck);

    const int gblocks = (n + 63) / 64;
    // layer 1: h1 = x @ W1 (bf16 out)
    mfma_gemm<F_IN, HH1, false, false, false><<<gblocks, blk, 0, stream>>>(x, W1t, nullptr, h1, n, HH1);
    agg_csr_bf16<32, 8><<<(n + 7) / 8, blk, 0, stream>>>(h1, rowptr, csr_src, dinv, b1, agg1, n);
    // layer 2: h2 = agg1 @ W2
    mfma_gemm<HH1, HH2, true, false, false><<<gblocks, blk, 0, stream>>>(agg1, W2t, nullptr, h2, n, HH2);
    agg_csr_bf16<16, 16><<<(n + 15) / 16, blk, 0, stream>>>(h2, rowptr, csr_src, dinv, b2, agg2, n);
    // head: out = agg2 @ Wh + bh (fp32 out, masked to 50 cols)
    mfma_gemm<HH2, 64, true, true, true><<<gblocks, blk, 0, stream>>>(agg2, Whtp, bh, out, n, FOUT);
}

// Round 8
// 137.719 us; speedup vs baseline: 1.3150x; 1.0802x over previous
//
#include <hip/hip_runtime.h>

#define F_IN 128
#define HH1 128
#define HH2 64
#define FOUT 50
#define EB 256          // edge-pass blocks (A1/A3)
#define NBUCK_MAX 256   // max coarse buckets (n <= 64k)

typedef __attribute__((ext_vector_type(8))) short short8;
typedef __attribute__((ext_vector_type(4))) short s16x4;
typedef __attribute__((ext_vector_type(4))) float f32x4;

__device__ inline short f2bf(float f) {  // RNE fp32->bf16
    union { float f; unsigned u; } v; v.f = f;
    unsigned r = v.u + 0x7fffu + ((v.u >> 16) & 1u);
    return (short)(r >> 16);
}
__device__ inline float bf2f(short s) {
    union { float f; unsigned u; } v; v.u = ((unsigned)(unsigned short)s) << 16;
    return v.f;
}

// Per-block int64-vs-int32 self-detection: int64 node ids < 2^31 have all-zero
// high (odd) words in the first 512 int32 words. Returns 1 if int64.
__device__ inline int detect64(const unsigned* raw) {
    __shared__ int s_is64;
    if (threadIdx.x == 0) s_is64 = 1;
    __syncthreads();
    if (raw[2 * threadIdx.x + 1] != 0u) atomicAnd(&s_is64, 0);
    __syncthreads();
    return s_is64;
}

// ---- A1: coarse histogram (dst>>8) per block + fused weight transpose -------
__global__ __launch_bounds__(256) void bucket_count(
    const int* __restrict__ raw, int E, int nbuck, int* __restrict__ parthist,
    const float* __restrict__ W1, const float* __restrict__ W2,
    const float* __restrict__ Wh, short* __restrict__ W1t,
    short* __restrict__ W2t, short* __restrict__ Wht) {
    __shared__ int hist[NBUCK_MAX];
    const int tid = threadIdx.x;
    int is64 = detect64((const unsigned*)raw);
    for (int k = tid; k < nbuck; k += 256) hist[k] = 0;
    __syncthreads();
    const int CH = (E + EB - 1) / EB;
    const int e0 = blockIdx.x * CH, e1 = min(E, e0 + CH);
    for (int e = e0 + tid; e < e1; e += 256) {
        int d = is64 ? raw[2 * (long)E + 2 * e] : raw[E + e];
        atomicAdd(&hist[d >> 8], 1);
    }
    __syncthreads();
    for (int k = tid; k < nbuck; k += 256) parthist[blockIdx.x * nbuck + k] = hist[k];
    // fused weight transpose (independent work)
    const int T1 = HH1 * F_IN, T2 = HH2 * HH1, T3 = 64 * HH2;
    int idx = blockIdx.x * 256 + tid;
    if (idx < T1) {
        int c = idx / F_IN, k = idx - c * F_IN;
        W1t[idx] = f2bf(W1[(long)k * HH1 + c]);
    } else if (idx < T1 + T2) {
        int i = idx - T1;
        int c = i / HH1, k = i - c * HH1;
        W2t[i] = f2bf(W2[(long)k * HH2 + c]);
    } else if (idx < T1 + T2 + T3) {
        int i = idx - T1 - T2;
        int c = i / HH2, k = i - c * HH2;
        Wht[i] = f2bf((c < FOUT) ? Wh[(long)k * FOUT + c] : 0.f);
    }
}

// ---- A2: column-sum + scan -> bucket bases; parthist -> per-block offsets ---
__global__ __launch_bounds__(256) void bucket_scan(
    int* __restrict__ parthist, int* __restrict__ bbase, int nbuck, int E) {
    __shared__ int sh[256];
    const int k = threadIdx.x;
    int sum = 0;
    if (k < nbuck)
        for (int b = 0; b < EB; ++b) sum += parthist[b * nbuck + k];
    int v = (k < nbuck) ? sum : 0;
    sh[k] = v;
    __syncthreads();
    for (int off = 1; off < 256; off <<= 1) {
        int t = (k >= off) ? sh[k - off] : 0;
        __syncthreads();
        sh[k] += t;
        __syncthreads();
    }
    int base = sh[k] - v;  // exclusive
    if (k < nbuck) bbase[k] = base;
    if (k == 0) bbase[nbuck] = E;
    if (k < nbuck) {
        int run = base;
        for (int b = 0; b < EB; ++b) {
            int t = parthist[b * nbuck + k];
            parthist[b * nbuck + k] = run;
            run += t;
        }
    }
}

// ---- A3: scatter (src,dst) into coarse buckets via LDS cursors --------------
__global__ __launch_bounds__(256) void bucket_scatter(
    const int* __restrict__ raw, int E, int nbuck,
    const int* __restrict__ parthist, int2* __restrict__ tmp) {
    __shared__ int cur[NBUCK_MAX];
    const int tid = threadIdx.x;
    int is64 = detect64((const unsigned*)raw);
    for (int k = tid; k < nbuck; k += 256) cur[k] = parthist[blockIdx.x * nbuck + k];
    __syncthreads();
    const int CH = (E + EB - 1) / EB;
    const int e0 = blockIdx.x * CH, e1 = min(E, e0 + CH);
    for (int e = e0 + tid; e < e1; e += 256) {
        int s, d;
        if (is64) {
            s = raw[2 * e];
            d = raw[2 * (long)E + 2 * e];
        } else {
            s = raw[e];
            d = raw[E + e];
        }
        int pos = atomicAdd(&cur[d >> 8], 1);
        tmp[pos] = make_int2(s, d);
    }
}

// ---- B: per-bucket fine sort -> rowptr, dinv, csr_src -----------------------
__global__ __launch_bounds__(256) void bucket_finalize(
    const int2* __restrict__ tmp, const int* __restrict__ bbase,
    int* __restrict__ rowptr, float* __restrict__ dinv,
    int* __restrict__ csr_src, int n, int nbuck) {
    __shared__ int deg[256];
    __shared__ int cur[256];
    __shared__ int sh[256];
    const int k = blockIdx.x;
    const int tid = threadIdx.x;
    const int b0 = bbase[k], b1 = bbase[k + 1];
    deg[tid] = 0;
    __syncthreads();
    for (int e = b0 + tid; e < b1; e += 256) atomicAdd(&deg[tmp[e].y & 255], 1);
    __syncthreads();
    int v = deg[tid];
    sh[tid] = v;
    __syncthreads();
    for (int off = 1; off < 256; off <<= 1) {
        int t = (tid >= off) ? sh[tid - off] : 0;
        __syncthreads();
        sh[tid] += t;
        __syncthreads();
    }
    int excl = sh[tid] - v;
    cur[tid] = excl;
    int node = (k << 8) + tid;
    if (node < n) {
        rowptr[node] = b0 + excl;
        dinv[node] = rsqrtf((float)v + 1.0f);  // +1 self-loop
    }
    if (k == 0 && tid == 0) rowptr[n] = bbase[nbuck];
    __syncthreads();
    for (int e = b0 + tid; e < b1; e += 256) {
        int2 sd = tmp[e];
        int p = atomicAdd(&cur[sd.y & 255], 1);
        csr_src[b0 + p] = sd.x;
    }
}

// ---- MFMA GEMM (layer 1 only): Y[M,NC] = X[M,K] @ Wt^T ----------------------
template <int K, int NC, bool IN_BF16, bool OUT_F32, bool BIAS>
__global__ __launch_bounds__(256) void mfma_gemm(const void* __restrict__ Xv,
                                                 const short* __restrict__ Wt,
                                                 const float* __restrict__ bias,
                                                 void* __restrict__ Yv, int M, int NCOUT) {
    const int tid = threadIdx.x;
    const int wave = tid >> 6;
    const int lane = tid & 63;
    const int l15 = lane & 15;
    const int kg = lane >> 4;
    const int rowbase = blockIdx.x * 64 + wave * 16;
    const int arow = rowbase + l15;
    constexpr int KS = K / 32;

    short8 af[KS];
    if (arow < M) {
        if (IN_BF16) {
            const short* xr = (const short*)Xv + (long)arow * K + kg * 8;
#pragma unroll
            for (int ks = 0; ks < KS; ++ks) af[ks] = *(const short8*)(xr + ks * 32);
        } else {
            const float* xr = (const float*)Xv + (long)arow * K + kg * 8;
#pragma unroll
            for (int ks = 0; ks < KS; ++ks) {
                float4 f0 = *(const float4*)(xr + ks * 32);
                float4 f1 = *(const float4*)(xr + ks * 32 + 4);
                short8 a;
                a[0] = f2bf(f0.x); a[1] = f2bf(f0.y); a[2] = f2bf(f0.z); a[3] = f2bf(f0.w);
                a[4] = f2bf(f1.x); a[5] = f2bf(f1.y); a[6] = f2bf(f1.z); a[7] = f2bf(f1.w);
                af[ks] = a;
            }
        }
    } else {
#pragma unroll
        for (int ks = 0; ks < KS; ++ks) af[ks] = (short8)0;
    }

    const int crowb = rowbase + kg * 4;
#pragma unroll
    for (int ct = 0; ct < NC / 16; ++ct) {
        const int col = ct * 16 + l15;
        const short* wr = Wt + (long)col * K + kg * 8;
        f32x4 acc = {0.f, 0.f, 0.f, 0.f};
#pragma unroll
        for (int ks = 0; ks < KS; ++ks) {
            short8 bf = *(const short8*)(wr + ks * 32);
            acc = __builtin_amdgcn_mfma_f32_16x16x32_bf16(af[ks], bf, acc, 0, 0, 0);
        }
        if (OUT_F32) {
            float* Y = (float*)Yv;
            float bv = BIAS ? bias[col] : 0.f;
#pragma unroll
            for (int j = 0; j < 4; ++j) {
                int r = crowb + j;
                if (r < M && col < NCOUT) Y[(long)r * NCOUT + col] = acc[j] + bv;
            }
        } else {
            short* Y = (short*)Yv;
#pragma unroll
            for (int j = 0; j < 4; ++j) {
                int r = crowb + j;
                if (r < M) Y[(long)r * NC + col] = f2bf(acc[j]);
            }
        }
    }
}

// ---- gather helpers ---------------------------------------------------------
template <int FPL>
__device__ inline void gather2(const short* p0, const short* p1, float c0,
                               float c1, float* acc) {
    if constexpr (FPL == 8) {
        short8 v0 = *(const short8*)p0;
        short8 v1 = *(const short8*)p1;
#pragma unroll
        for (int j = 0; j < 8; ++j) acc[j] = fmaf(c0, bf2f(v0[j]), acc[j]);
#pragma unroll
        for (int j = 0; j < 8; ++j) acc[j] = fmaf(c1, bf2f(v1[j]), acc[j]);
    } else {
        s16x4 v0 = *(const s16x4*)p0;
        s16x4 v1 = *(const s16x4*)p1;
#pragma unroll
        for (int j = 0; j < 4; ++j) acc[j] = fmaf(c0, bf2f(v0[j]), acc[j]);
#pragma unroll
        for (int j = 0; j < 4; ++j) acc[j] = fmaf(c1, bf2f(v1[j]), acc[j]);
    }
}
template <int FPL>
__device__ inline void gather1(const short* p0, float c0, float* acc) {
    if constexpr (FPL == 8) {
        short8 v0 = *(const short8*)p0;
#pragma unroll
        for (int j = 0; j < 8; ++j) acc[j] = fmaf(c0, bf2f(v0[j]), acc[j]);
    } else {
        s16x4 v0 = *(const s16x4*)p0;
#pragma unroll
        for (int j = 0; j < 4; ++j) acc[j] = fmaf(c0, bf2f(v0[j]), acc[j]);
    }
}

// ---- fused aggregate + GEMM -------------------------------------------------
// Per block: 16 nodes. Phase 1: 16 lanes/node gather-aggregate
//   t[i] = relu(bias_pre + dinv[i]^2*h[i] + sum_e dinv[s]*dinv[i]*h[s]) (bf16)
// into LDS tile [16][FW+8]. Phase 2: 4 waves, wave w computes cols w*16..w*16+15
// of tile @ Wt^T (Wt is [64][FW]), writes bf16 Y[n][64] or fp32 out + bias_post.
template <int FW, bool OUT_F32>
__global__ __launch_bounds__(256) void agg_mm(
    const short* __restrict__ h, const int* __restrict__ rowptr,
    const int* __restrict__ csr_src, const float* __restrict__ dinv,
    const float* __restrict__ bias_pre, const short* __restrict__ Wt,
    const float* __restrict__ bias_post, void* __restrict__ Yv, int n,
    int ncreal) {
    constexpr int FPL = FW / 16;   // bf16 feats per lane (8 or 4)
    constexpr int LDW = FW + 8;    // padded row: 2-way-max bank pattern
    constexpr int KS = FW / 32;
    __shared__ short tile[16][LDW];
    const int tid = threadIdx.x;
    const int grp = tid >> 4;
    const int l16 = tid & 15;
    const int node = blockIdx.x * 16 + grp;

    float acc[FPL];
#pragma unroll
    for (int j = 0; j < FPL; ++j) acc[j] = 0.f;

    if (node < n) {
        const float di = dinv[node];
#pragma unroll
        for (int j = 0; j < FPL; ++j) acc[j] = bias_pre[l16 * FPL + j];
        gather1<FPL>(h + (long)node * FW + l16 * FPL, di * di, acc);  // self-loop
        int e = rowptr[node];
        const int end = rowptr[node + 1];
        for (; e + 1 < end; e += 2) {
            int s0 = csr_src[e];
            int s1 = csr_src[e + 1];
            float c0 = dinv[s0] * di;
            float c1 = dinv[s1] * di;
            gather2<FPL>(h + (long)s0 * FW + l16 * FPL,
                         h + (long)s1 * FW + l16 * FPL, c0, c1, acc);
        }
        if (e < end) {
            int s0 = csr_src[e];
            gather1<FPL>(h + (long)s0 * FW + l16 * FPL, dinv[s0] * di, acc);
        }
    }
    // relu -> bf16 -> LDS tile (OOB rows get zeros: acc stayed 0)
    if constexpr (FPL == 8) {
        short8 o;
#pragma unroll
        for (int j = 0; j < 8; ++j) o[j] = f2bf(fmaxf(acc[j], 0.f));
        *(short8*)&tile[grp][l16 * 8] = o;
    } else {
        s16x4 o;
#pragma unroll
        for (int j = 0; j < 4; ++j) o[j] = f2bf(fmaxf(acc[j], 0.f));
        *(s16x4*)&tile[grp][l16 * 4] = o;
    }
    __syncthreads();

    // MFMA: tile[16][FW] @ Wt^T -> [16][64]
    const int wave = tid >> 6;
    const int lane = tid & 63;
    const int l15 = lane & 15;
    const int kg = lane >> 4;
    const int col = wave * 16 + l15;
    short8 af[KS];
#pragma unroll
    for (int ks = 0; ks < KS; ++ks)
        af[ks] = *(const short8*)&tile[l15][kg * 8 + ks * 32];
    f32x4 c2 = {0.f, 0.f, 0.f, 0.f};
    const short* wr = Wt + (long)col * FW + kg * 8;
#pragma unroll
    for (int ks = 0; ks < KS; ++ks) {
        short8 bfr = *(const short8*)(wr + ks * 32);
        c2 = __builtin_amdgcn_mfma_f32_16x16x32_bf16(af[ks], bfr, c2, 0, 0, 0);
    }
    const int rb = blockIdx.x * 16 + kg * 4;
    if (OUT_F32) {
        float* Y = (float*)Yv;
#pragma unroll
        for (int j = 0; j < 4; ++j) {
            int g = rb + j;
            if (g < n && col < ncreal)
                Y[(long)g * ncreal + col] = c2[j] + bias_post[col];
        }
    } else {
        short* Y = (short*)Yv;
#pragma unroll
        for (int j = 0; j < 4; ++j) {
            int g = rb + j;
            if (g < n) Y[(long)g * 64 + col] = f2bf(c2[j]);
        }
    }
}

// ---- launch -----------------------------------------------------------------
static inline size_t al256(size_t x) { return (x + 255) & ~(size_t)255; }

extern "C" void kernel_launch(void* const* d_in, const int* in_sizes, int n_in,
                              void* d_out, int out_size, void* d_ws, size_t ws_size,
                              hipStream_t stream) {
    const float* x    = (const float*)d_in[0];
    const int*   eraw = (const int*)d_in[1];
    const float* W1   = (const float*)d_in[2];
    const float* b1   = (const float*)d_in[3];
    const float* W2   = (const float*)d_in[4];
    const float* b2   = (const float*)d_in[5];
    const float* Wh   = (const float*)d_in[6];
    const float* bh   = (const float*)d_in[7];
    float* out = (float*)d_out;
    const int n = in_sizes[0] / F_IN;
    const int E = in_sizes[1] / 2;
    const int nbuck = (n + 255) >> 8;  // 196 for n=50k

    // ---- workspace layout ----
    char* p = (char*)d_ws;
    float* dinv     = (float*)p; p += al256((size_t)n * 4);
    int*   rowptr   = (int*)p;   p += al256((size_t)(n + 1) * 4);
    int*   parthist = (int*)p;   p += al256((size_t)EB * nbuck * 4);
    int*   bbase    = (int*)p;   p += al256((size_t)(nbuck + 1) * 4);
    int*   csr_src  = (int*)p;   p += al256((size_t)E * 4);
    short* W1t      = (short*)p; p += al256((size_t)HH1 * F_IN * 2);
    short* W2t      = (short*)p; p += al256((size_t)HH2 * HH1 * 2);
    short* Whtp     = (short*)p; p += al256((size_t)64 * HH2 * 2);
    short* bigA     = (short*)p; p += al256((size_t)n * HH1 * 2);   // 12.8 MB
    short* bigB     = (short*)p;                                    // 6.4 MB
    // (src,dst) bucket buffer overlays bigA (dead before GEMM1 writes h1)
    int2* tmp   = (int2*)bigA;
    short* h1   = bigA;   // [n][128] bf16
    short* h2   = bigB;   // [n][64]  bf16

    dim3 blk(256);
    // CSR build: two-level bucket sort, all fine atomics in LDS
    bucket_count<<<EB, blk, 0, stream>>>(eraw, E, nbuck, parthist, W1, W2, Wh, W1t, W2t, Whtp);
    bucket_scan<<<1, blk, 0, stream>>>(parthist, bbase, nbuck, E);
    bucket_scatter<<<EB, blk, 0, stream>>>(eraw, E, nbuck, parthist, tmp);
    bucket_finalize<<<nbuck, blk, 0, stream>>>(tmp, bbase, rowptr, dinv, csr_src, n, nbuck);

    // layer 1 GEMM: h1 = x @ W1 (bf16 out)
    mfma_gemm<F_IN, HH1, false, false, false><<<(n + 63) / 64, blk, 0, stream>>>(
        x, W1t, nullptr, h1, n, HH1);
    // fused: agg(h1)+b1+relu -> @W2 -> h2
    agg_mm<HH1, false><<<(n + 15) / 16, blk, 0, stream>>>(
        h1, rowptr, csr_src, dinv, b1, W2t, nullptr, h2, n, HH2);
    // fused: agg(h2)+b2+relu -> @Wh + bh -> out (fp32, 50 cols)
    agg_mm<HH2, true><<<(n + 15) / 16, blk, 0, stream>>>(
        h2, rowptr, csr_src, dinv, b2, Whtp, bh, out, n, FOUT);
}

// Round 9
// 121.410 us; speedup vs baseline: 1.4916x; 1.1343x over previous
//
#include <hip/hip_runtime.h>

#define F_IN 128
#define HH1 128
#define HH2 64
#define FOUT 50
#define EB 256          // edge-pass blocks (A1/A3)
#define NBUCK_MAX 256   // max coarse buckets (n <= 64k)

typedef __attribute__((ext_vector_type(8))) short short8;
typedef __attribute__((ext_vector_type(4))) short s16x4;
typedef __attribute__((ext_vector_type(4))) float f32x4;

__device__ inline short f2bf(float f) {  // RNE fp32->bf16
    union { float f; unsigned u; } v; v.f = f;
    unsigned r = v.u + 0x7fffu + ((v.u >> 16) & 1u);
    return (short)(r >> 16);
}
__device__ inline float bf2f(short s) {
    union { float f; unsigned u; } v; v.u = ((unsigned)(unsigned short)s) << 16;
    return v.f;
}

// Per-block int64-vs-int32 self-detection: int64 node ids < 2^31 have all-zero
// high (odd) words in the first 512 int32 words. Returns 1 if int64.
__device__ inline int detect64(const unsigned* raw) {
    __shared__ int s_is64;
    if (threadIdx.x == 0) s_is64 = 1;
    __syncthreads();
    if (raw[2 * threadIdx.x + 1] != 0u) atomicAnd(&s_is64, 0);
    __syncthreads();
    return s_is64;
}

// ---- A1: coarse histogram (dst>>8) per block + fused weight transpose -------
__global__ __launch_bounds__(256) void bucket_count(
    const int* __restrict__ raw, int E, int nbuck, int* __restrict__ parthist,
    const float* __restrict__ W1, const float* __restrict__ W2,
    const float* __restrict__ Wh, short* __restrict__ W1t,
    short* __restrict__ W2t, short* __restrict__ Wht) {
    __shared__ int hist[NBUCK_MAX];
    const int tid = threadIdx.x;
    int is64 = detect64((const unsigned*)raw);
    for (int k = tid; k < nbuck; k += 256) hist[k] = 0;
    __syncthreads();
    const int CH = (E + EB - 1) / EB;
    const int e0 = blockIdx.x * CH, e1 = min(E, e0 + CH);
    for (int e = e0 + tid; e < e1; e += 256) {
        int d = is64 ? raw[2 * (long)E + 2 * e] : raw[E + e];
        atomicAdd(&hist[d >> 8], 1);
    }
    __syncthreads();
    for (int k = tid; k < nbuck; k += 256) parthist[blockIdx.x * nbuck + k] = hist[k];
    // fused weight transpose (independent work)
    const int T1 = HH1 * F_IN, T2 = HH2 * HH1, T3 = 64 * HH2;
    int idx = blockIdx.x * 256 + tid;
    if (idx < T1) {
        int c = idx / F_IN, k = idx - c * F_IN;
        W1t[idx] = f2bf(W1[(long)k * HH1 + c]);
    } else if (idx < T1 + T2) {
        int i = idx - T1;
        int c = i / HH1, k = i - c * HH1;
        W2t[i] = f2bf(W2[(long)k * HH2 + c]);
    } else if (idx < T1 + T2 + T3) {
        int i = idx - T1 - T2;
        int c = i / HH2, k = i - c * HH2;
        Wht[i] = f2bf((c < FOUT) ? Wh[(long)k * FOUT + c] : 0.f);
    }
}

// ---- A2: column-sum + scan -> bucket bases; parthist -> per-block offsets ---
__global__ __launch_bounds__(256) void bucket_scan(
    int* __restrict__ parthist, int* __restrict__ bbase, int nbuck, int E) {
    __shared__ int sh[256];
    const int k = threadIdx.x;
    int sum = 0;
    if (k < nbuck)
        for (int b = 0; b < EB; ++b) sum += parthist[b * nbuck + k];
    int v = (k < nbuck) ? sum : 0;
    sh[k] = v;
    __syncthreads();
    for (int off = 1; off < 256; off <<= 1) {
        int t = (k >= off) ? sh[k - off] : 0;
        __syncthreads();
        sh[k] += t;
        __syncthreads();
    }
    int base = sh[k] - v;  // exclusive
    if (k < nbuck) bbase[k] = base;
    if (k == 0) bbase[nbuck] = E;
    if (k < nbuck) {
        int run = base;
        for (int b = 0; b < EB; ++b) {
            int t = parthist[b * nbuck + k];
            parthist[b * nbuck + k] = run;
            run += t;
        }
    }
}

// ---- A3 + layer-1 GEMM merged in one dispatch -------------------------------
// blocks [0, EB): scatter (src,dst) into coarse buckets via LDS cursors
// blocks [EB, ...): h1 = bf16(x) @ W1t^T  (independent work, overlapped)
__global__ __launch_bounds__(256) void scatter_gemm1(
    const int* __restrict__ raw, int E, int nbuck,
    const int* __restrict__ parthist, int2* __restrict__ tmp,
    const float* __restrict__ x, const short* __restrict__ W1t,
    short* __restrict__ h1, int n) {
    const int tid = threadIdx.x;
    if (blockIdx.x < EB) {
        __shared__ int cur[NBUCK_MAX];
        int is64 = detect64((const unsigned*)raw);
        for (int k = tid; k < nbuck; k += 256) cur[k] = parthist[blockIdx.x * nbuck + k];
        __syncthreads();
        const int CH = (E + EB - 1) / EB;
        const int e0 = blockIdx.x * CH, e1 = min(E, e0 + CH);
        for (int e = e0 + tid; e < e1; e += 256) {
            int s, d;
            if (is64) {
                s = raw[2 * e];
                d = raw[2 * (long)E + 2 * e];
            } else {
                s = raw[e];
                d = raw[E + e];
            }
            int pos = atomicAdd(&cur[d >> 8], 1);
            tmp[pos] = make_int2(s, d);
        }
        return;
    }
    // ---- GEMM1 part ----
    const int bid = blockIdx.x - EB;
    const int wave = tid >> 6;
    const int lane = tid & 63;
    const int l15 = lane & 15;
    const int kg = lane >> 4;
    const int rowbase = bid * 64 + wave * 16;
    const int arow = rowbase + l15;
    constexpr int KS = F_IN / 32;

    short8 af[KS];
    if (arow < n) {
        const float* xr = x + (long)arow * F_IN + kg * 8;
#pragma unroll
        for (int ks = 0; ks < KS; ++ks) {
            float4 f0 = *(const float4*)(xr + ks * 32);
            float4 f1 = *(const float4*)(xr + ks * 32 + 4);
            short8 a;
            a[0] = f2bf(f0.x); a[1] = f2bf(f0.y); a[2] = f2bf(f0.z); a[3] = f2bf(f0.w);
            a[4] = f2bf(f1.x); a[5] = f2bf(f1.y); a[6] = f2bf(f1.z); a[7] = f2bf(f1.w);
            af[ks] = a;
        }
    } else {
#pragma unroll
        for (int ks = 0; ks < KS; ++ks) af[ks] = (short8)0;
    }
    const int crowb = rowbase + kg * 4;
#pragma unroll
    for (int ct = 0; ct < HH1 / 16; ++ct) {
        const int col = ct * 16 + l15;
        const short* wr = W1t + (long)col * F_IN + kg * 8;
        f32x4 acc = {0.f, 0.f, 0.f, 0.f};
#pragma unroll
        for (int ks = 0; ks < KS; ++ks) {
            short8 bfr = *(const short8*)(wr + ks * 32);
            acc = __builtin_amdgcn_mfma_f32_16x16x32_bf16(af[ks], bfr, acc, 0, 0, 0);
        }
#pragma unroll
        for (int j = 0; j < 4; ++j) {
            int r = crowb + j;
            if (r < n) h1[(long)r * HH1 + col] = f2bf(acc[j]);
        }
    }
}

// ---- B: per-bucket fine sort -> rowptr, dinv, csr_src -----------------------
__global__ __launch_bounds__(256) void bucket_finalize(
    const int2* __restrict__ tmp, const int* __restrict__ bbase,
    int* __restrict__ rowptr, float* __restrict__ dinv,
    int* __restrict__ csr_src, int n, int nbuck) {
    __shared__ int deg[256];
    __shared__ int cur[256];
    __shared__ int sh[256];
    const int k = blockIdx.x;
    const int tid = threadIdx.x;
    const int b0 = bbase[k], b1 = bbase[k + 1];
    deg[tid] = 0;
    __syncthreads();
    for (int e = b0 + tid; e < b1; e += 256) atomicAdd(&deg[tmp[e].y & 255], 1);
    __syncthreads();
    int v = deg[tid];
    sh[tid] = v;
    __syncthreads();
    for (int off = 1; off < 256; off <<= 1) {
        int t = (tid >= off) ? sh[tid - off] : 0;
        __syncthreads();
        sh[tid] += t;
        __syncthreads();
    }
    int excl = sh[tid] - v;
    cur[tid] = excl;
    int node = (k << 8) + tid;
    if (node < n) {
        rowptr[node] = b0 + excl;
        dinv[node] = rsqrtf((float)v + 1.0f);  // +1 self-loop
    }
    if (k == 0 && tid == 0) rowptr[n] = bbase[nbuck];
    __syncthreads();
    for (int e = b0 + tid; e < b1; e += 256) {
        int2 sd = tmp[e];
        int p = atomicAdd(&cur[sd.y & 255], 1);
        csr_src[b0 + p] = sd.x;
    }
}

// ---- gather helpers ---------------------------------------------------------
template <int FPL>
__device__ inline void gather1(const short* p0, float c0, float* acc) {
    if constexpr (FPL == 8) {
        short8 v0 = *(const short8*)p0;
#pragma unroll
        for (int j = 0; j < 8; ++j) acc[j] = fmaf(c0, bf2f(v0[j]), acc[j]);
    } else {
        s16x4 v0 = *(const s16x4*)p0;
#pragma unroll
        for (int j = 0; j < 4; ++j) acc[j] = fmaf(c0, bf2f(v0[j]), acc[j]);
    }
}

// ---- fused aggregate + GEMM -------------------------------------------------
// Per block: 16 nodes. Phase 1: 16 lanes/node gather-aggregate (4-wide ILP)
//   t[i] = relu(bias_pre + dinv[i]^2*h[i] + sum_e dinv[s]*dinv[i]*h[s]) (bf16)
// into LDS tile [16][FW+8]. Phase 2: 4 waves, wave w computes cols w*16..w*16+15
// of tile @ Wt^T (Wt is [64][FW]), writes bf16 Y[n][64] or fp32 out + bias_post.
template <int FW, bool OUT_F32>
__global__ __launch_bounds__(256) void agg_mm(
    const short* __restrict__ h, const int* __restrict__ rowptr,
    const int* __restrict__ csr_src, const float* __restrict__ dinv,
    const float* __restrict__ bias_pre, const short* __restrict__ Wt,
    const float* __restrict__ bias_post, void* __restrict__ Yv, int n,
    int ncreal) {
    constexpr int FPL = FW / 16;   // bf16 feats per lane (8 or 4)
    constexpr int LDW = FW + 8;    // padded row
    constexpr int KS = FW / 32;
    __shared__ short tile[16][LDW];
    const int tid = threadIdx.x;
    const int grp = tid >> 4;
    const int l16 = tid & 15;
    const int node = blockIdx.x * 16 + grp;

    float acc[FPL];
#pragma unroll
    for (int j = 0; j < FPL; ++j) acc[j] = 0.f;

    if (node < n) {
        const float di = dinv[node];
#pragma unroll
        for (int j = 0; j < FPL; ++j) acc[j] = bias_pre[l16 * FPL + j];
        gather1<FPL>(h + (long)node * FW + l16 * FPL, di * di, acc);  // self-loop
        int e = rowptr[node];
        const int end = rowptr[node + 1];
        for (; e + 3 < end; e += 4) {  // 4 independent gathers in flight
            int s0 = csr_src[e];
            int s1 = csr_src[e + 1];
            int s2 = csr_src[e + 2];
            int s3 = csr_src[e + 3];
            const short* p0 = h + (long)s0 * FW + l16 * FPL;
            const short* p1 = h + (long)s1 * FW + l16 * FPL;
            const short* p2 = h + (long)s2 * FW + l16 * FPL;
            const short* p3 = h + (long)s3 * FW + l16 * FPL;
            float c0 = dinv[s0] * di;
            float c1 = dinv[s1] * di;
            float c2 = dinv[s2] * di;
            float c3 = dinv[s3] * di;
            if constexpr (FPL == 8) {
                short8 v0 = *(const short8*)p0;
                short8 v1 = *(const short8*)p1;
                short8 v2 = *(const short8*)p2;
                short8 v3 = *(const short8*)p3;
#pragma unroll
                for (int j = 0; j < 8; ++j) acc[j] = fmaf(c0, bf2f(v0[j]), acc[j]);
#pragma unroll
                for (int j = 0; j < 8; ++j) acc[j] = fmaf(c1, bf2f(v1[j]), acc[j]);
#pragma unroll
                for (int j = 0; j < 8; ++j) acc[j] = fmaf(c2, bf2f(v2[j]), acc[j]);
#pragma unroll
                for (int j = 0; j < 8; ++j) acc[j] = fmaf(c3, bf2f(v3[j]), acc[j]);
            } else {
                s16x4 v0 = *(const s16x4*)p0;
                s16x4 v1 = *(const s16x4*)p1;
                s16x4 v2 = *(const s16x4*)p2;
                s16x4 v3 = *(const s16x4*)p3;
#pragma unroll
                for (int j = 0; j < 4; ++j) acc[j] = fmaf(c0, bf2f(v0[j]), acc[j]);
#pragma unroll
                for (int j = 0; j < 4; ++j) acc[j] = fmaf(c1, bf2f(v1[j]), acc[j]);
#pragma unroll
                for (int j = 0; j < 4; ++j) acc[j] = fmaf(c2, bf2f(v2[j]), acc[j]);
#pragma unroll
                for (int j = 0; j < 4; ++j) acc[j] = fmaf(c3, bf2f(v3[j]), acc[j]);
            }
        }
        for (; e < end; ++e) {
            int s0 = csr_src[e];
            gather1<FPL>(h + (long)s0 * FW + l16 * FPL, dinv[s0] * di, acc);
        }
    }
    // relu -> bf16 -> LDS tile (OOB rows get zeros: acc stayed 0)
    if constexpr (FPL == 8) {
        short8 o;
#pragma unroll
        for (int j = 0; j < 8; ++j) o[j] = f2bf(fmaxf(acc[j], 0.f));
        *(short8*)&tile[grp][l16 * 8] = o;
    } else {
        s16x4 o;
#pragma unroll
        for (int j = 0; j < 4; ++j) o[j] = f2bf(fmaxf(acc[j], 0.f));
        *(s16x4*)&tile[grp][l16 * 4] = o;
    }
    __syncthreads();

    // MFMA: tile[16][FW] @ Wt^T -> [16][64]
    const int wave = tid >> 6;
    const int lane = tid & 63;
    const int l15 = lane & 15;
    const int kg = lane >> 4;
    const int col = wave * 16 + l15;
    short8 af[KS];
#pragma unroll
    for (int ks = 0; ks < KS; ++ks)
        af[ks] = *(const short8*)&tile[l15][kg * 8 + ks * 32];
    f32x4 c2 = {0.f, 0.f, 0.f, 0.f};
    const short* wr = Wt + (long)col * FW + kg * 8;
#pragma unroll
    for (int ks = 0; ks < KS; ++ks) {
        short8 bfr = *(const short8*)(wr + ks * 32);
        c2 = __builtin_amdgcn_mfma_f32_16x16x32_bf16(af[ks], bfr, c2, 0, 0, 0);
    }
    const int rb = blockIdx.x * 16 + kg * 4;
    if (OUT_F32) {
        float* Y = (float*)Yv;
#pragma unroll
        for (int j = 0; j < 4; ++j) {
            int g = rb + j;
            if (g < n && col < ncreal)
                Y[(long)g * ncreal + col] = c2[j] + bias_post[col];
        }
    } else {
        short* Y = (short*)Yv;
#pragma unroll
        for (int j = 0; j < 4; ++j) {
            int g = rb + j;
            if (g < n) Y[(long)g * 64 + col] = f2bf(c2[j]);
        }
    }
}

// ---- launch -----------------------------------------------------------------
static inline size_t al256(size_t x) { return (x + 255) & ~(size_t)255; }

extern "C" void kernel_launch(void* const* d_in, const int* in_sizes, int n_in,
                              void* d_out, int out_size, void* d_ws, size_t ws_size,
                              hipStream_t stream) {
    const float* x    = (const float*)d_in[0];
    const int*   eraw = (const int*)d_in[1];
    const float* W1   = (const float*)d_in[2];
    const float* b1   = (const float*)d_in[3];
    const float* W2   = (const float*)d_in[4];
    const float* b2   = (const float*)d_in[5];
    const float* Wh   = (const float*)d_in[6];
    const float* bh   = (const float*)d_in[7];
    float* out = (float*)d_out;
    const int n = in_sizes[0] / F_IN;
    const int E = in_sizes[1] / 2;
    const int nbuck = (n + 255) >> 8;  // 196 for n=50k

    // ---- workspace layout (tmp no longer overlays h1: scatter runs concurrent
    //      with gemm1 writing h1) ----
    char* p = (char*)d_ws;
    float* dinv     = (float*)p; p += al256((size_t)n * 4);
    int*   rowptr   = (int*)p;   p += al256((size_t)(n + 1) * 4);
    int*   parthist = (int*)p;   p += al256((size_t)EB * nbuck * 4);
    int*   bbase    = (int*)p;   p += al256((size_t)(nbuck + 1) * 4);
    int*   csr_src  = (int*)p;   p += al256((size_t)E * 4);
    short* W1t      = (short*)p; p += al256((size_t)HH1 * F_IN * 2);
    short* W2t      = (short*)p; p += al256((size_t)HH2 * HH1 * 2);
    short* Whtp     = (short*)p; p += al256((size_t)64 * HH2 * 2);
    int2*  tmp      = (int2*)p;  p += al256((size_t)E * 8);         // 5 MB
    short* h1       = (short*)p; p += al256((size_t)n * HH1 * 2);   // 12.8 MB
    short* h2       = (short*)p;                                    // 6.4 MB

    dim3 blk(256);
    // CSR build (two-level bucket sort, LDS atomics) overlapped with GEMM1
    bucket_count<<<EB, blk, 0, stream>>>(eraw, E, nbuck, parthist, W1, W2, Wh, W1t, W2t, Whtp);
    bucket_scan<<<1, blk, 0, stream>>>(parthist, bbase, nbuck, E);
    scatter_gemm1<<<EB + (n + 63) / 64, blk, 0, stream>>>(
        eraw, E, nbuck, parthist, tmp, x, W1t, h1, n);
    bucket_finalize<<<nbuck, blk, 0, stream>>>(tmp, bbase, rowptr, dinv, csr_src, n, nbuck);

    // fused: agg(h1)+b1+relu -> @W2 -> h2
    agg_mm<HH1, false><<<(n + 15) / 16, blk, 0, stream>>>(
        h1, rowptr, csr_src, dinv, b1, W2t, nullptr, h2, n, HH2);
    // fused: agg(h2)+b2+relu -> @Wh + bh -> out (fp32, 50 cols)
    agg_mm<HH2, true><<<(n + 15) / 16, blk, 0, stream>>>(
        h2, rowptr, csr_src, dinv, b2, Whtp, bh, out, n, FOUT);
}